// Round 3
// baseline (372.295 us; speedup 1.0000x reference)
//
#include <hip/hip_runtime.h>

// ContinuousAxialDW: out = x + axialH(x) + axialW(x)
// x: [B=8, C=96, H=256, W=256] fp32
//
// R1: per-channel integer stencils prebuilt into d_ws (tiny pre-pass kernel).
// R2: 4x4 register blocking + XCD swizzle. FETCH 340->98 MB, but compiler
//     sank the loads (VGPR=64) -> latency-bound at 129 us.
// R3: cooperative LDS staging (global_load_lds, halo-zeroed tile) -> ~106 us.
//     Still stall-bound: one barrier per WG lifetime = serial stage->drain->
//     compute; all pipes at <=50%.
// R4 (this round): persistent WGs + double-buffered 2-phase pipeline.
//     512 WGs x 24 tiles; per iteration: STAGE(buf^1, t+1) issued BEFORE
//     compute(buf, t); one barrier (vmcnt drain) per tile -> HBM latency
//     hides under compute deterministically. Plus: per-channel staging row
//     skip from ballot'd stencil support, halo cols zeroed once.

constexpr int B = 8, C = 96, H = 256, W = 256;
constexpr int KT = 7;              // taps per axis
constexpr int HALO = 8;            // integer-tap radius (covers r <= ~2.3)
constexpr int NW = 2 * HALO + 1;   // 17
constexpr int RPB = 16;            // output rows per tile (4 waves x 4 rows)
constexpr int SR = RPB + 2 * HALO; // 32 staged rows
constexpr int LDW = W + 16;        // 272: 8-col zero halo each side
constexpr int TILES = B * C * (H / RPB);   // 12288
constexpr int GRID = 512;                  // persistent WGs (2 per CU)
constexpr int TPW = TILES / GRID;          // 24 tiles per WG
constexpr int TPX = TILES / 8;             // 1536 tiles per XCD

// d_ws layout: [0 .. C*NW)            = wtv (vertical / H-axis stencil)
//              [C*NW .. 2*C*NW)       = wth (horizontal / W-axis stencil)
//              int region at 2*C*NW   = per-channel {smin, smax} staged-row range

__global__ __launch_bounds__(64) void build_stencils(
    const float* __restrict__ wh,
    const float* __restrict__ ww,
    const float* __restrict__ rp,
    float* __restrict__ ws)
{
    const int c = blockIdx.x;        // 0..C-1
    const int d = threadIdx.x;       // 0..63, only d < NW active
    if (d >= NW) return;

    float r = rp[0];
    if (r < 1.0f) r = 1.0f;

    float av = 0.f, aw = 0.f;
#pragma unroll
    for (int i = 0; i < KT; ++i) {
        float s   = (float)(i - 3) * r;   // pixel shift of tap i
        float d0f = floorf(s);
        int   d0  = (int)d0f;
        float f   = s - d0f;              // constant bilinear frac
        float thv = wh[c * KT + i];
        float twv = ww[c * KT + i];
        if (d - HALO == d0)     { av = fmaf(thv, 1.f - f, av); aw = fmaf(twv, 1.f - f, aw); }
        if (d - HALO == d0 + 1) { av = fmaf(thv, f, av);       aw = fmaf(twv, f, aw); }
    }
    ws[c * NW + d]          = av;
    ws[C * NW + c * NW + d] = aw;

    // vertical-tap support -> staged-row range [smin, smax] for this channel.
    // Row i (LDS-relative) is read iff i in [lo, 15+hi] (vertical, tap range
    // [lo,hi]) or i in [8,23] (center rows: residual + horizontal).
    unsigned long long m = __ballot(av != 0.f);   // bit d set iff wtv[c][d] != 0
    if (d == 0) {
        int lo = 8, hi = 8;                        // degenerate all-zero case
        if (m) { lo = __ffsll((long long)m) - 1; hi = 63 - __clzll((long long)m); }
        int* wsi = (int*)ws;
        wsi[2 * C * NW + 2 * c]     = min(lo, 8);       // smin
        wsi[2 * C * NW + 2 * c + 1] = max(15 + hi, 23); // smax
    }
}

__global__ __launch_bounds__(256, 2) void axialdw_kernel(
    const float* __restrict__ x,
    const float* __restrict__ ws,
    float* __restrict__ out)
{
    __shared__ __align__(16) float tile[2][SR][LDW];   // 2 x 34,816 B

    const int g     = blockIdx.x;
    const int tbase = (g & 7) * TPX + (g >> 3) * TPW;  // XCD-chunked tile run
    const int tid   = threadIdx.x;
    const int wave  = tid >> 6;
    const int lane  = tid & 63;
    const int w0    = lane * 4;
    const int rbase = wave * 4;
    const int* wsi  = (const int*)ws;

    // ---- zero halo cols ONCE (never overwritten): 2 buf x 32 rows x 4 quads ----
    {
        const int q    = tid & 3;
        const int i    = (tid >> 2) & 31;
        const int bsel = tid >> 7;
        const int col  = (q < 2) ? q * 4 : (W + 8 + (q - 2) * 4);  // 0,4,264,268
        *(float4*)&tile[bsel][i][col] = make_float4(0.f, 0.f, 0.f, 0.f);
    }

    // ---- stage tile t into buf (support-skipped, coalesced, no VGPR trip) ----
    auto stage = [&](float (*buf)[LDW], int t) {
        const int hb = t & 15;            // t % (H/RPB)
        const int bc = t >> 4;
        const int c  = bc % C;
        const int smin = wsi[2 * C * NW + 2 * c];
        const int smax = wsi[2 * C * NW + 2 * c + 1];
        const float* plane = x + (size_t)bc * (H * W);
        const int gr0 = hb * RPB - HALO;
#pragma unroll
        for (int it = 0; it < SR / 4; ++it) {
            const int i = wave + 4 * it;            // wave-uniform LDS row
            if (i < smin || i > smax) continue;     // never read for this c
            const int gr = gr0 + i;
            if (gr >= 0 && gr < H) {
                const float* gsrc = plane + (size_t)gr * W + w0;
                __builtin_amdgcn_global_load_lds(
                    (const __attribute__((address_space(1))) void*)gsrc,
                    (__attribute__((address_space(3))) void*)&buf[i][HALO],
                    16, 0, 0);
            } else {
                *(float4*)&buf[i][HALO + w0] = make_float4(0.f, 0.f, 0.f, 0.f);
            }
        }
    };

    // ---- compute + store tile t from buf ----
    auto compute_store = [&](const float (*buf)[LDW], int t) {
        const int hb = t & 15;
        const int bc = t >> 4;
        const int c  = bc % C;

        float wtv[NW], wth[NW];                     // uniform -> scalar loads
#pragma unroll
        for (int d = 0; d < NW; ++d) {
            wtv[d] = ws[c * NW + d];
            wth[d] = ws[C * NW + c * NW + d];
        }

        float acc[4][4], ctr[4][4];
#pragma unroll
        for (int rr = 0; rr < 4; ++rr) {
            const float* lrow = &buf[rbase + 8 + rr][w0];   // span cols
            float sp[20];
#pragma unroll
            for (int k = 0; k < 5; ++k) {
                const float4 v = *(const float4*)(lrow + 4 * k);
                sp[4 * k + 0] = v.x; sp[4 * k + 1] = v.y;
                sp[4 * k + 2] = v.z; sp[4 * k + 3] = v.w;
            }
#pragma unroll
            for (int e = 0; e < 4; ++e) {
                ctr[rr][e] = sp[HALO + e];          // x itself
                acc[rr][e] = sp[HALO + e];          // residual
            }
#pragma unroll
            for (int d = 0; d < NW; ++d) {
                const float wg = wth[d];
                if (wg != 0.f) {                    // uniform zero-tap skip
#pragma unroll
                    for (int e = 0; e < 4; ++e)
                        acc[rr][e] = fmaf(wg, sp[d + e], acc[rr][e]);
                }
            }
        }

        // vertical: source LDS row = rbase + s, feeding acc[rr] via d = s - rr
#pragma unroll
        for (int s = 0; s < 20; ++s) {
            float v[4];
            if (s >= 8 && s <= 11) {
#pragma unroll
                for (int e = 0; e < 4; ++e) v[e] = ctr[s - 8][e];
            } else {
                bool need = false;
#pragma unroll
                for (int rr = 0; rr < 4; ++rr) {
                    const int d = s - rr;
                    if (d >= 0 && d < NW) need = need || (wtv[d] != 0.f);
                }
                if (!need) continue;                // uniform skip
                const float4 tv = *(const float4*)&buf[rbase + s][HALO + w0];
                v[0] = tv.x; v[1] = tv.y; v[2] = tv.z; v[3] = tv.w;
            }
#pragma unroll
            for (int rr = 0; rr < 4; ++rr) {
                const int d = s - rr;
                if (d >= 0 && d < NW) {
                    const float wg = wtv[d];
#pragma unroll
                    for (int e = 0; e < 4; ++e)
                        acc[rr][e] = fmaf(wg, v[e], acc[rr][e]);
                }
            }
        }

        float* obase = out + (size_t)bc * (H * W)
                     + (size_t)(hb * RPB + rbase) * W + w0;
#pragma unroll
        for (int rr = 0; rr < 4; ++rr) {
            float4 o;
            o.x = acc[rr][0]; o.y = acc[rr][1]; o.z = acc[rr][2]; o.w = acc[rr][3];
            *(float4*)(obase + (size_t)rr * W) = o;
        }
    };

    // ---- 2-phase pipeline: stage(t+1) issued before compute(t) ----
    stage(tile[0], tbase);
    __syncthreads();                                // drain prologue stage
#pragma unroll 2
    for (int k = 0; k < TPW; ++k) {
        if (k + 1 < TPW) stage(tile[(k + 1) & 1], tbase + k + 1);
        compute_store(tile[k & 1], tbase + k);
        __syncthreads();   // vmcnt drain: stage(k+1) landed; buf reads done
    }
}

extern "C" void kernel_launch(void* const* d_in, const int* in_sizes, int n_in,
                              void* d_out, int out_size, void* d_ws, size_t ws_size,
                              hipStream_t stream) {
    const float* x  = (const float*)d_in[0];
    const float* wh = (const float*)d_in[1];
    const float* ww = (const float*)d_in[2];
    const float* rp = (const float*)d_in[3];
    float* out = (float*)d_out;
    float* ws  = (float*)d_ws;

    build_stencils<<<C, 64, 0, stream>>>(wh, ww, rp, ws);
    axialdw_kernel<<<GRID, 256, 0, stream>>>(x, ws, out);
}

// Round 4
// 341.959 us; speedup vs baseline: 1.0887x; 1.0887x over previous
//
#include <hip/hip_runtime.h>

// ContinuousAxialDW: out = x + axialH(x) + axialW(x)
// x: [B=8, C=96, H=256, W=256] fp32
//
// R1: per-channel integer stencils prebuilt into d_ws (tiny pre-pass kernel).
// R2: 4x4 register blocking + XCD swizzle. FETCH 340->98 MB, but compiler
//     sank the loads (VGPR=64) -> latency-bound at 129 us.
// R3: cooperative LDS staging (global_load_lds, halo-zeroed tile) -> ~106 us.
// R4: FAILED (170 us): persistent WGs + explicit double-buffer pipeline.
//     Bank conflicts 0 -> 1.26e7 (stage writes vs compute reads concurrent on
//     LDS arbiter), occupancy 39 -> 21%. Explicit pipelining < TLP. Reverted.
// R5 (this round): R3 structure, TALLER tile for occupancy + less halo waste.
//     512-thread WG (8 waves), 32 output rows, 48 staged rows (52.2 KB LDS)
//     -> 3 WG/CU = 24 waves/CU (75% ceiling, was 50%), row redundancy
//     1.5x (was 2.0x). ctr[] register cache dropped + launch_bounds(512,6)
//     to keep VGPR <= 85 so 6 waves/SIMD actually fit.

constexpr int B = 8, C = 96, H = 256, W = 256;
constexpr int KT = 7;              // taps per axis
constexpr int HALO = 8;            // integer-tap radius (covers r <= ~2.3)
constexpr int NW = 2 * HALO + 1;   // 17
constexpr int RPB = 32;            // output rows per WG (8 waves x 4 rows)
constexpr int SR = RPB + 2 * HALO; // 48 staged rows
constexpr int LDW = W + 16;        // 272: 8-col zero halo each side
constexpr int TILES = B * C * (H / RPB);   // 6144
constexpr int TPX = TILES / 8;             // 768 tiles per XCD

// d_ws layout: [0 .. C*NW)            = wtv (vertical / H-axis stencil)
//              [C*NW .. 2*C*NW)       = wth (horizontal / W-axis stencil)
//              int region at 2*C*NW   = per-channel {lo, hi} vertical tap support

__global__ __launch_bounds__(64) void build_stencils(
    const float* __restrict__ wh,
    const float* __restrict__ ww,
    const float* __restrict__ rp,
    float* __restrict__ ws)
{
    const int c = blockIdx.x;        // 0..C-1
    const int d = threadIdx.x;       // 0..63, only d < NW active
    if (d >= NW) return;

    float r = rp[0];
    if (r < 1.0f) r = 1.0f;

    float av = 0.f, aw = 0.f;
#pragma unroll
    for (int i = 0; i < KT; ++i) {
        float s   = (float)(i - 3) * r;   // pixel shift of tap i
        float d0f = floorf(s);
        int   d0  = (int)d0f;
        float f   = s - d0f;              // constant bilinear frac
        float thv = wh[c * KT + i];
        float twv = ww[c * KT + i];
        if (d - HALO == d0)     { av = fmaf(thv, 1.f - f, av); aw = fmaf(twv, 1.f - f, aw); }
        if (d - HALO == d0 + 1) { av = fmaf(thv, f, av);       aw = fmaf(twv, f, aw); }
    }
    ws[c * NW + d]          = av;
    ws[C * NW + c * NW + d] = aw;

    // vertical-tap support [lo, hi] in d-index (0..16); consumed by main
    // kernel to skip staging rows no channel tap ever reads.
    unsigned long long m = __ballot(av != 0.f);
    if (d == 0) {
        int lo = HALO, hi = HALO;                  // degenerate all-zero case
        if (m) { lo = __ffsll((long long)m) - 1; hi = 63 - __clzll((long long)m); }
        int* wsi = (int*)ws;
        wsi[2 * C * NW + 2 * c]     = lo;
        wsi[2 * C * NW + 2 * c + 1] = hi;
    }
}

__global__ __launch_bounds__(512, 6) void axialdw_kernel(
    const float* __restrict__ x,
    const float* __restrict__ ws,
    float* __restrict__ out)
{
    __shared__ __align__(16) float tile[SR][LDW];   // 48 x 272 x 4B = 52,224 B

    // ---- XCD-aware bijective swizzle (nwg = 6144, divisible by 8) ----
    const int bid = blockIdx.x;
    const int lb  = (bid & 7) * TPX + (bid >> 3);

    const int hb   = lb & (H / RPB - 1);         // h-chunk within plane (0..7)
    const int bc   = lb >> 3;                    // (b,c) plane index
    const int c    = bc % C;
    const int tid  = threadIdx.x;
    const int wave = tid >> 6;                   // 0..7
    const int lane = tid & 63;
    const int w0   = lane * 4;
    const int rbase = wave * 4;                  // wave's first output row (rel)

    const int* wsi  = (const int*)ws;
    const int lo    = wsi[2 * C * NW + 2 * c];
    const int hi    = wsi[2 * C * NW + 2 * c + 1];
    const int smin  = min(lo, HALO);             // rows read: vertical [lo, 31+hi]
    const int smax  = max(RPB - 1 + hi, RPB + 7);//            center   [8, 39]

    const float* plane = x + (size_t)bc * (H * W);
    const int gr0 = hb * RPB - HALO;             // global row of LDS row 0

    // ---- zero 8-col horizontal halos once (stage never touches them) ----
    if (tid < SR * 4) {
        const int i   = tid >> 2;
        const int q   = tid & 3;
        const int col = (q < 2) ? q * 4 : (W + 8 + (q - 2) * 4);  // 0,4,264,268
        *(float4*)&tile[i][col] = make_float4(0.f, 0.f, 0.f, 0.f);
    }

    // ---- stage: wave w loads LDS rows w, w+8, ..., w+40 (support-skipped) ----
#pragma unroll
    for (int it = 0; it < SR / 8; ++it) {
        const int i = wave + 8 * it;             // wave-uniform LDS row
        if (i < smin || i > smax) continue;      // never read for this channel
        const int gr = gr0 + i;
        if (gr >= 0 && gr < H) {
            const float* gsrc = plane + (size_t)gr * W + w0;     // per-lane
            __builtin_amdgcn_global_load_lds(
                (const __attribute__((address_space(1))) void*)gsrc,
                (__attribute__((address_space(3))) void*)&tile[i][HALO],
                16, 0, 0);
        } else {
            *(float4*)&tile[i][HALO + w0] = make_float4(0.f, 0.f, 0.f, 0.f);
        }
    }

    // block-uniform stencil loads (uniform c -> scalar loads, SGPR-resident)
    float wtv[NW], wth[NW];
#pragma unroll
    for (int d = 0; d < NW; ++d) {
        wtv[d] = ws[c * NW + d];
        wth[d] = ws[C * NW + c * NW + d];
    }

    __syncthreads();   // drains vmcnt (global_load_lds) + lgkmcnt (ds_write)

    float acc[4][4];
#pragma unroll
    for (int rr = 0; rr < 4; ++rr)
#pragma unroll
        for (int e = 0; e < 4; ++e) acc[rr][e] = 0.f;

    // ---- vertical: LDS source row rbase+t feeds acc[rr] via tap d = t-rr ----
#pragma unroll
    for (int t = 0; t < 20; ++t) {
        bool need = false;
#pragma unroll
        for (int rr = 0; rr < 4; ++rr) {
            const int d = t - rr;
            if (d >= 0 && d < NW) need = need || (wtv[d] != 0.f);
        }
        if (!need) continue;                     // wave-uniform skip
        const float4 v = *(const float4*)&tile[rbase + t][HALO + w0];
#pragma unroll
        for (int rr = 0; rr < 4; ++rr) {
            const int d = t - rr;
            if (d >= 0 && d < NW) {
                const float wg = wtv[d];
#pragma unroll
                for (int e = 0; e < 4; ++e) {
                    const float s = (&v.x)[e];
                    acc[rr][e] = fmaf(wg, s, acc[rr][e]);
                }
            }
        }
    }

    // ---- horizontal + residual, then store (row at a time) ----
    float* obase = out + (size_t)bc * (H * W)
                 + (size_t)(hb * RPB + rbase) * W + w0;
#pragma unroll
    for (int rr = 0; rr < 4; ++rr) {
        const float* lrow = &tile[rbase + 8 + rr][w0];   // span cols w0..w0+19
        float sp[20];
#pragma unroll
        for (int k = 0; k < 5; ++k) {
            const float4 v = *(const float4*)(lrow + 4 * k);
            sp[4 * k + 0] = v.x; sp[4 * k + 1] = v.y;
            sp[4 * k + 2] = v.z; sp[4 * k + 3] = v.w;
        }
#pragma unroll
        for (int e = 0; e < 4; ++e)
            acc[rr][e] += sp[HALO + e];                  // residual x
#pragma unroll
        for (int d = 0; d < NW; ++d) {
            const float wg = wth[d];
            if (wg != 0.f) {                             // uniform zero-tap skip
#pragma unroll
                for (int e = 0; e < 4; ++e)
                    acc[rr][e] = fmaf(wg, sp[d + e], acc[rr][e]);
            }
        }
        float4 o;
        o.x = acc[rr][0]; o.y = acc[rr][1]; o.z = acc[rr][2]; o.w = acc[rr][3];
        *(float4*)(obase + (size_t)rr * W) = o;
    }
}

extern "C" void kernel_launch(void* const* d_in, const int* in_sizes, int n_in,
                              void* d_out, int out_size, void* d_ws, size_t ws_size,
                              hipStream_t stream) {
    const float* x  = (const float*)d_in[0];
    const float* wh = (const float*)d_in[1];
    const float* ww = (const float*)d_in[2];
    const float* rp = (const float*)d_in[3];
    float* out = (float*)d_out;
    float* ws  = (float*)d_ws;

    build_stencils<<<C, 64, 0, stream>>>(wh, ww, rp, ws);
    axialdw_kernel<<<TILES, 512, 0, stream>>>(x, ws, out);
}

// Round 5
// 341.908 us; speedup vs baseline: 1.0889x; 1.0001x over previous
//
#include <hip/hip_runtime.h>

// ContinuousAxialDW: out = x + axialH(x) + axialW(x)
// x: [B=8, C=96, H=256, W=256] fp32
//
// R1: per-channel integer stencils prebuilt into d_ws (tiny pre-pass kernel).
// R2: 4x4 register blocking + XCD swizzle. 129 us, latency-bound.
// R3: cooperative LDS staging (global_load_lds, halo-zeroed tile) -> ~106 us.
// R4: FAILED (170 us): explicit double-buffer pipeline (bank conflicts + occ drop).
// R5: NEUTRAL (~109 us): taller tile aimed at 24 waves/CU, but VGPR ~88 ->
//     allocator rounded down to 2 WG/CU = 16 waves/CU, same residency as R3.
//     Diagnosis: all pipes <=45%, 16 waves/CU cap -> still latency-bound.
// R6 (this round): hit the 32 waves/CU hardware cap.
//     512-thr WG, 16 output rows, 32 staged rows (34.8 KB -> 4 WG/CU on LDS),
//     2 output rows PER THREAD (8 waves x 2 rows) so live state ~45 regs,
//     __launch_bounds__(512, 8) forces VGPR <= 64 -> 8 waves/SIMD.
//     2x the independent waves covering the stage-drain + LDS-read latencies.

constexpr int B = 8, C = 96, H = 256, W = 256;
constexpr int KT = 7;              // taps per axis
constexpr int HALO = 8;            // integer-tap radius (covers r <= ~2.3)
constexpr int NW = 2 * HALO + 1;   // 17
constexpr int RPB = 16;            // output rows per WG (8 waves x 2 rows)
constexpr int SR = RPB + 2 * HALO; // 32 staged rows
constexpr int LDW = W + 16;        // 272: 8-col zero halo each side
constexpr int TILES = B * C * (H / RPB);   // 12288
constexpr int TPX = TILES / 8;             // 1536 tiles per XCD

// d_ws layout: [0 .. C*NW)            = wtv (vertical / H-axis stencil)
//              [C*NW .. 2*C*NW)       = wth (horizontal / W-axis stencil)
//              int region at 2*C*NW   = per-channel {lo, hi} vertical tap support

__global__ __launch_bounds__(64) void build_stencils(
    const float* __restrict__ wh,
    const float* __restrict__ ww,
    const float* __restrict__ rp,
    float* __restrict__ ws)
{
    const int c = blockIdx.x;        // 0..C-1
    const int d = threadIdx.x;       // 0..63, only d < NW active
    if (d >= NW) return;

    float r = rp[0];
    if (r < 1.0f) r = 1.0f;

    float av = 0.f, aw = 0.f;
#pragma unroll
    for (int i = 0; i < KT; ++i) {
        float s   = (float)(i - 3) * r;   // pixel shift of tap i
        float d0f = floorf(s);
        int   d0  = (int)d0f;
        float f   = s - d0f;              // constant bilinear frac
        float thv = wh[c * KT + i];
        float twv = ww[c * KT + i];
        if (d - HALO == d0)     { av = fmaf(thv, 1.f - f, av); aw = fmaf(twv, 1.f - f, aw); }
        if (d - HALO == d0 + 1) { av = fmaf(thv, f, av);       aw = fmaf(twv, f, aw); }
    }
    ws[c * NW + d]          = av;
    ws[C * NW + c * NW + d] = aw;

    // vertical-tap support [lo, hi] in d-index (0..16); consumed by main
    // kernel to skip staging rows no channel tap ever reads.
    unsigned long long m = __ballot(av != 0.f);
    if (d == 0) {
        int lo = HALO, hi = HALO;                  // degenerate all-zero case
        if (m) { lo = __ffsll((long long)m) - 1; hi = 63 - __clzll((long long)m); }
        int* wsi = (int*)ws;
        wsi[2 * C * NW + 2 * c]     = lo;
        wsi[2 * C * NW + 2 * c + 1] = hi;
    }
}

__global__ __launch_bounds__(512, 8) void axialdw_kernel(
    const float* __restrict__ x,
    const float* __restrict__ ws,
    float* __restrict__ out)
{
    __shared__ __align__(16) float tile[SR][LDW];   // 32 x 272 x 4B = 34,816 B

    // ---- XCD-aware bijective swizzle (nwg = 12288, divisible by 8) ----
    const int bid = blockIdx.x;
    const int lb  = (bid & 7) * TPX + (bid >> 3);

    const int hb   = lb & (H / RPB - 1);         // h-chunk within plane (0..15)
    const int bc   = lb >> 4;                    // (b,c) plane index
    const int c    = bc % C;
    const int tid  = threadIdx.x;
    const int wave = tid >> 6;                   // 0..7
    const int lane = tid & 63;
    const int w0   = lane * 4;
    const int rbase = wave * 2;                  // wave's first output row (rel)

    // block-uniform stencil + support loads FIRST (s_load latency hides
    // under the staging issue below)
    const int* wsi  = (const int*)ws;
    const int lo    = wsi[2 * C * NW + 2 * c];
    const int hi    = wsi[2 * C * NW + 2 * c + 1];
    const int smin  = min(lo, HALO);             // rows read: vertical [lo, 15+hi]
    const int smax  = max(RPB - 1 + hi, RPB + 7);//            center   [8, 23]
    float wtv[NW], wth[NW];
#pragma unroll
    for (int d = 0; d < NW; ++d) {
        wtv[d] = ws[c * NW + d];
        wth[d] = ws[C * NW + c * NW + d];
    }

    const float* plane = x + (size_t)bc * (H * W);
    const int gr0 = hb * RPB - HALO;             // global row of LDS row 0

    // ---- zero 8-col horizontal halos (stage never touches them) ----
    if (tid < SR * 4) {
        const int i   = tid >> 2;
        const int q   = tid & 3;
        const int col = (q < 2) ? q * 4 : (W + 8 + (q - 2) * 4);  // 0,4,264,268
        *(float4*)&tile[i][col] = make_float4(0.f, 0.f, 0.f, 0.f);
    }

    // ---- stage: wave w loads LDS rows w, w+8, w+16, w+24 (support-skipped) ----
#pragma unroll
    for (int it = 0; it < SR / 8; ++it) {
        const int i = wave + 8 * it;             // wave-uniform LDS row
        if (i < smin || i > smax) continue;      // never read for this channel
        const int gr = gr0 + i;
        if (gr >= 0 && gr < H) {
            const float* gsrc = plane + (size_t)gr * W + w0;     // per-lane
            __builtin_amdgcn_global_load_lds(
                (const __attribute__((address_space(1))) void*)gsrc,
                (__attribute__((address_space(3))) void*)&tile[i][HALO],
                16, 0, 0);
        } else {
            *(float4*)&tile[i][HALO + w0] = make_float4(0.f, 0.f, 0.f, 0.f);
        }
    }

    __syncthreads();   // drains vmcnt (global_load_lds) + lgkmcnt (ds_write)

    float acc[2][4];
#pragma unroll
    for (int rr = 0; rr < 2; ++rr)
#pragma unroll
        for (int e = 0; e < 4; ++e) acc[rr][e] = 0.f;

    // ---- vertical: LDS source row rbase+t feeds acc[rr] via tap d = t-rr ----
#pragma unroll
    for (int t = 0; t < 18; ++t) {
        bool need = false;
#pragma unroll
        for (int rr = 0; rr < 2; ++rr) {
            const int d = t - rr;
            if (d >= 0 && d < NW) need = need || (wtv[d] != 0.f);
        }
        if (!need) continue;                     // wave-uniform skip
        const float4 v = *(const float4*)&tile[rbase + t][HALO + w0];
#pragma unroll
        for (int rr = 0; rr < 2; ++rr) {
            const int d = t - rr;
            if (d >= 0 && d < NW) {
                const float wg = wtv[d];
                if (wg != 0.f) {
                    acc[rr][0] = fmaf(wg, v.x, acc[rr][0]);
                    acc[rr][1] = fmaf(wg, v.y, acc[rr][1]);
                    acc[rr][2] = fmaf(wg, v.z, acc[rr][2]);
                    acc[rr][3] = fmaf(wg, v.w, acc[rr][3]);
                }
            }
        }
    }

    // ---- horizontal + residual, then store (row at a time) ----
    float* obase = out + (size_t)bc * (H * W)
                 + (size_t)(hb * RPB + rbase) * W + w0;
#pragma unroll
    for (int rr = 0; rr < 2; ++rr) {
        const float* lrow = &tile[rbase + 8 + rr][w0];   // span cols w0..w0+19
        float sp[20];
#pragma unroll
        for (int k = 0; k < 5; ++k) {
            const float4 v = *(const float4*)(lrow + 4 * k);
            sp[4 * k + 0] = v.x; sp[4 * k + 1] = v.y;
            sp[4 * k + 2] = v.z; sp[4 * k + 3] = v.w;
        }
#pragma unroll
        for (int e = 0; e < 4; ++e)
            acc[rr][e] += sp[HALO + e];                  // residual x
#pragma unroll
        for (int d = 0; d < NW; ++d) {
            const float wg = wth[d];
            if (wg != 0.f) {                             // uniform zero-tap skip
#pragma unroll
                for (int e = 0; e < 4; ++e)
                    acc[rr][e] = fmaf(wg, sp[d + e], acc[rr][e]);
            }
        }
        float4 o;
        o.x = acc[rr][0]; o.y = acc[rr][1]; o.z = acc[rr][2]; o.w = acc[rr][3];
        *(float4*)(obase + (size_t)rr * W) = o;
    }
}

extern "C" void kernel_launch(void* const* d_in, const int* in_sizes, int n_in,
                              void* d_out, int out_size, void* d_ws, size_t ws_size,
                              hipStream_t stream) {
    const float* x  = (const float*)d_in[0];
    const float* wh = (const float*)d_in[1];
    const float* ww = (const float*)d_in[2];
    const float* rp = (const float*)d_in[3];
    float* out = (float*)d_out;
    float* ws  = (float*)d_ws;

    build_stencils<<<C, 64, 0, stream>>>(wh, ww, rp, ws);
    axialdw_kernel<<<TILES, 512, 0, stream>>>(x, ws, out);
}